// Round 4
// baseline (418.167 us; speedup 1.0000x reference)
//
#include <hip/hip_runtime.h>
#include <hip/hip_bf16.h>
#include <cstddef>
#include <cstdint>

// ---------------------------------------------------------------------------
// Problem constants
// ---------------------------------------------------------------------------
#define B_   128
#define N_   8
#define C_   1024
#define FS_  14
#define POS_ 196            // 14*14
#define P_   20
#define HWC_ 9              // 3*3 cells
#define ROWS_ 9216          // B*N*HWC
#define CMID_ 256
#define FEATD_ 2304         // CMID*HWC
#define H1_  1024
#define O_   27

typedef __attribute__((ext_vector_type(8))) short bf16x8;   // 8 bf16 (4 VGPRs)
typedef __attribute__((ext_vector_type(4))) float f32x4;

// async global->LDS, 16B per lane; LDS dest = wave-uniform base + lane*16
__device__ __forceinline__ void gld16(const void* g, void* l) {
    __builtin_amdgcn_global_load_lds(
        (const __attribute__((address_space(1))) unsigned int*)g,
        (__attribute__((address_space(3))) unsigned int*)l, 16, 0, 0);
}

// Precomputed bilinear tap: 4 weights (0.25 and validity folded in) + the two
// row-base offsets. Pairs (v00,v01) and (v10,v11) are always adjacent because
// clamping forces lx=0 at x0=13 (w1/w3 become 0), so reading [off, off+1] is
// always correct and stays inside the 197-float padded LDS slot.
struct Tap { float w0, w1, w2, w3; int offA, offB, pad0, pad1; };  // 32 B

// ---------------------------------------------------------------------------
// Kernel 0: tap precompute — one thread per (b,n,cell,tap), 36864 total
// ---------------------------------------------------------------------------
__global__ __launch_bounds__(256) void taps_kernel(
    const float* __restrict__ boxes, Tap* __restrict__ taps)
{
    int idx = blockIdx.x * 256 + threadIdx.x;
    if (idx >= B_ * N_ * HWC_ * 4) return;
    int bn   = idx / 36;           // b*8+n
    int rem  = idx - bn * 36;
    int cell = rem >> 2;
    int tap  = rem & 3;
    int chh = cell / 3, cww = cell % 3;
    int si = tap >> 1, sj = tap & 1;
    const float* bx = boxes + (size_t)bn * 4;
    float x1 = bx[0], y1 = bx[1], x2 = bx[2], y2 = bx[3];
    float bw = (x2 - x1) * (1.0f / 3.0f);
    float bh = (y2 - y1) * (1.0f / 3.0f);
    float yy = y1 + ((float)(2 * chh + si) + 0.5f) * 0.5f * bh;
    float xx = x1 + ((float)(2 * cww + sj) + 0.5f) * 0.5f * bw;
    bool valid = (yy > -1.0f) && (yy < (float)FS_) &&
                 (xx > -1.0f) && (xx < (float)FS_);
    float y = fminf(fmaxf(yy, 0.0f), (float)(FS_ - 1));
    float x = fminf(fmaxf(xx, 0.0f), (float)(FS_ - 1));
    int y0 = (int)floorf(y);
    int x0 = (int)floorf(x);
    float ly = y - (float)y0, lx = x - (float)x0;
    float hy = 1.0f - ly,     hx = 1.0f - lx;
    float s = valid ? 0.25f : 0.0f;
    Tap tp;
    tp.w0 = s * hy * hx;
    tp.w1 = s * hy * lx;
    tp.w2 = s * ly * hx;
    tp.w3 = s * ly * lx;
    tp.offA = y0 * FS_ + x0;
    tp.offB = min(y0 + 1, FS_ - 1) * FS_ + x0;
    tp.pad0 = 0; tp.pad1 = 0;
    taps[idx] = tp;
}

// ---------------------------------------------------------------------------
// Kernel 1a: split-K partials of Wc = w2 @ w1
//   grid (16,4,8), 64x64 tile, K-slice 64 -> 512 blocks (2/CU), fp32
// ---------------------------------------------------------------------------
__global__ __launch_bounds__(256) void wcombine_split_kernel(
    const float* __restrict__ w1,   // (512,1024)
    const float* __restrict__ w2,   // (256,512)
    float* __restrict__ wpart)      // (8,256,1024) fp32
{
    const int tid = threadIdx.x;
    const int tx = tid & 15, ty = tid >> 4;
    const int c0 = blockIdx.x * 64;
    const int o0 = blockIdx.y * 64;
    const int kb = blockIdx.z * 64;
    __shared__ __align__(16) float As[16][68];
    __shared__ __align__(16) float Bs[16][68];
    float acc[4][4] = {};
    for (int k0 = kb; k0 < kb + 64; k0 += 16) {
        for (int i = tid; i < 64 * 16; i += 256) {
            int k = i & 15, m = i >> 4;
            As[k][m] = w2[(size_t)(o0 + m) * 512 + k0 + k];
        }
        for (int i = tid; i < 64 * 16; i += 256) {
            int n = i & 63, k = i >> 6;
            Bs[k][n] = w1[(size_t)(k0 + k) * 1024 + c0 + n];
        }
        __syncthreads();
        #pragma unroll
        for (int k = 0; k < 16; ++k) {
            float4 a = *(const float4*)&As[k][ty * 4];
            float4 b = *(const float4*)&Bs[k][tx * 4];
            float av[4] = {a.x, a.y, a.z, a.w};
            float bv[4] = {b.x, b.y, b.z, b.w};
            #pragma unroll
            for (int i = 0; i < 4; ++i)
                #pragma unroll
                for (int j = 0; j < 4; ++j)
                    acc[i][j] += av[i] * bv[j];
        }
        __syncthreads();
    }
    float* dst = wpart + (size_t)blockIdx.z * (256 * 1024);
    for (int i = 0; i < 4; ++i) {
        float4 v = make_float4(acc[i][0], acc[i][1], acc[i][2], acc[i][3]);
        *(float4*)&dst[(size_t)(o0 + ty * 4 + i) * 1024 + c0 + tx * 4] = v;
    }
}

// ---------------------------------------------------------------------------
// Kernel 1b: Wc = bf16( sum_z wpart[z] )
// ---------------------------------------------------------------------------
__global__ __launch_bounds__(256) void wc_reduce_kernel(
    const float* __restrict__ wpart, __hip_bfloat16* __restrict__ Wc)
{
    int idx = blockIdx.x * 256 + threadIdx.x;
    float s = 0.f;
    #pragma unroll
    for (int z = 0; z < 8; ++z) s += wpart[(size_t)z * (256 * 1024) + idx];
    Wc[idx] = __float2bfloat16(s);
}

// ---------------------------------------------------------------------------
// Kernel 2: ROI align with precomputed taps -> roi_bf16 (9216 x 1024)
//   grid (4,128), block 576 = 64 chan-lanes x 9 cells; per output:
//   4 taps x (2 pair LDS reads + 4 FMA) — weights/offsets are wave-uniform.
// ---------------------------------------------------------------------------
__global__ __launch_bounds__(576) void roi_kernel(
    const float* __restrict__ fmap,   // (128,1024,14,14)
    const Tap* __restrict__ taps,     // (128,8,9,4)
    __hip_bfloat16* __restrict__ roi_mat)
{
    const int b = blockIdx.y;
    const int q = blockIdx.x;
    const int tid = threadIdx.x;
    const int c_local = tid & 63;
    const int cell = tid >> 6;          // 0..8
    __shared__ float stage[64 * 197];   // stride 197: 2-way max aliasing (free)

    for (int chunk = 0; chunk < 4; ++chunk) {
        const int c0 = q * 256 + chunk * 64;
        __syncthreads();
        const float* src = fmap + (size_t)(b * C_ + c0) * POS_;
        for (int i4 = tid; i4 < (64 * POS_) / 4; i4 += 576) {
            float4 v = ((const float4*)src)[i4];
            int base = i4 * 4;
            int c = base / POS_;
            int pos = base - c * POS_;
            float* dst = &stage[c * 197 + pos];
            dst[0] = v.x; dst[1] = v.y; dst[2] = v.z; dst[3] = v.w;
        }
        __syncthreads();

        const float* ch_ptr = &stage[c_local * 197];
        for (int n = 0; n < N_; ++n) {
            const Tap* tp = taps + ((size_t)(b * N_ + n) * HWC_ + cell) * 4;
            float acc = 0.0f;
            #pragma unroll
            for (int t = 0; t < 4; ++t) {
                float4 w = *(const float4*)&tp[t].w0;
                int2 off = *(const int2*)&tp[t].offA;
                const float* pa = ch_ptr + off.x;
                const float* pb = ch_ptr + off.y;
                float a0 = pa[0], a1 = pa[1];
                float b0 = pb[0], b1 = pb[1];
                acc += w.x * a0 + w.y * a1 + w.z * b0 + w.w * b1;
            }
            roi_mat[(size_t)((b * N_ + n) * HWC_ + cell) * C_ + c0 + c_local] =
                __float2bfloat16(acc);
        }
    }
}

// ---------------------------------------------------------------------------
// MFMA GEMM: C = A(M x K) @ B(N x K)^T, A/B bf16 K-contiguous rows.
// 64x64 tile, BK=64, 4 waves in 2x2, each wave 2x2 of 16x16x32 MFMA.
// XOR-swizzled LDS realized by permuting the per-lane GLOBAL source address.
// EPI 0: scatter to feat[bn*2304 + hw*256 + o]; EPI 1: bias+relu -> h1.
// ---------------------------------------------------------------------------
template<int EPI>
__global__ __launch_bounds__(256) void mfma_gemm_kernel(
    const __hip_bfloat16* __restrict__ A,
    const __hip_bfloat16* __restrict__ Bm,
    const float* __restrict__ bias,
    float* __restrict__ C, int K)
{
    const int tid = threadIdx.x;
    const int wave = tid >> 6, lane = tid & 63;
    const int r0 = blockIdx.y * 64, n0 = blockIdx.x * 64;
    const int wm = (wave >> 1) * 32, wn = (wave & 1) * 32;
    const int m16 = lane & 15, quad = lane >> 4;
    __shared__ __align__(16) __hip_bfloat16 As[64 * 64];
    __shared__ __align__(16) __hip_bfloat16 Bs[64 * 64];

    f32x4 acc[2][2];
    #pragma unroll
    for (int i = 0; i < 2; ++i)
        #pragma unroll
        for (int j = 0; j < 2; ++j)
            acc[i][j] = (f32x4){0.f, 0.f, 0.f, 0.f};

    const int s0 = wave * 64 + lane;
    const int ms0 = s0 >> 3, cs0 = (s0 & 7) ^ (ms0 & 7);
    const int s1 = 256 + s0;
    const int ms1 = s1 >> 3, cs1 = (s1 & 7) ^ (ms1 & 7);
    const size_t rA0 = (size_t)(r0 + ms0) * K + cs0 * 8;
    const size_t rA1 = (size_t)(r0 + ms1) * K + cs1 * 8;
    const size_t rB0 = (size_t)(n0 + ms0) * K + cs0 * 8;
    const size_t rB1 = (size_t)(n0 + ms1) * K + cs1 * 8;

    for (int k0 = 0; k0 < K; k0 += 64) {
        gld16(A + rA0 + k0, &As[wave * 512]);
        gld16(Bm + rB0 + k0, &Bs[wave * 512]);
        gld16(A + rA1 + k0, &As[2048 + wave * 512]);
        gld16(Bm + rB1 + k0, &Bs[2048 + wave * 512]);
        __syncthreads();
        #pragma unroll
        for (int ks = 0; ks < 2; ++ks) {
            bf16x8 af[2], bfv[2];
            #pragma unroll
            for (int t = 0; t < 2; ++t) {
                int m = wm + t * 16 + m16;
                int cp = (ks * 4 + quad) ^ (m & 7);
                af[t] = *(const bf16x8*)&As[(m * 8 + cp) * 8];
                int n = wn + t * 16 + m16;
                int cq = (ks * 4 + quad) ^ (n & 7);
                bfv[t] = *(const bf16x8*)&Bs[(n * 8 + cq) * 8];
            }
            #pragma unroll
            for (int i = 0; i < 2; ++i)
                #pragma unroll
                for (int j = 0; j < 2; ++j)
                    acc[i][j] = __builtin_amdgcn_mfma_f32_16x16x32_bf16(
                        af[i], bfv[j], acc[i][j], 0, 0, 0);
        }
        __syncthreads();
    }

    // C/D layout: col = lane&15, row = quad*4 + reg
    #pragma unroll
    for (int i = 0; i < 2; ++i) {
        #pragma unroll
        for (int j = 0; j < 2; ++j) {
            int col = n0 + wn + j * 16 + m16;
            int rbase = r0 + wm + i * 16 + quad * 4;
            if (EPI == 0) {
                #pragma unroll
                for (int g = 0; g < 4; ++g) {
                    int r = rbase + g;
                    int bn = r / 9, hw = r - bn * 9;
                    C[(size_t)bn * FEATD_ + hw * 256 + col] = acc[i][j][g];
                }
            } else {
                float bv = bias[col];
                #pragma unroll
                for (int g = 0; g < 4; ++g) {
                    int r = rbase + g;
                    float v = acc[i][j][g] + bv;
                    C[(size_t)r * H1_ + col] = v > 0.f ? v : 0.f;
                }
            }
        }
    }
}

// ---------------------------------------------------------------------------
// fc1_w (1024 x 2304 fp32, k = o*9+hw) -> bf16 permuted (k' = hw*256+o)
// ---------------------------------------------------------------------------
__global__ __launch_bounds__(256) void fc1w_perm_kernel(
    const float* __restrict__ src, __hip_bfloat16* __restrict__ dst)
{
    int h = blockIdx.y;
    int d2 = blockIdx.x * 256 + threadIdx.x;   // hw*256+o
    int hw = d2 >> 8, o = d2 & 255;
    dst[(size_t)h * FEATD_ + d2] =
        __float2bfloat16(src[(size_t)h * FEATD_ + o * HWC_ + hw]);
}

// ---------------------------------------------------------------------------
// inv[b][p] = n with pids[b][n]==p else -1
// ---------------------------------------------------------------------------
__global__ __launch_bounds__(64) void invmap_kernel(
    const int* __restrict__ pids, int* __restrict__ inv)
{
    int b = blockIdx.x;
    int p = threadIdx.x;
    if (p < P_) {
        int v = -1;
        for (int n = 0; n < N_; ++n)
            if (pids[b * N_ + n] == p) v = n;
        inv[b * P_ + p] = v;
    }
}

// ---------------------------------------------------------------------------
// mean_b[p][d] = (1/128) sum_b feat[b, inv[b][p], d]
// ---------------------------------------------------------------------------
__global__ __launch_bounds__(256) void meanb_kernel(
    const float* __restrict__ feat, const int* __restrict__ inv,
    float* __restrict__ mean_b)
{
    int p = blockIdx.x;
    int d = blockIdx.y * 256 + threadIdx.x;
    float acc = 0.0f;
    for (int b = 0; b < B_; ++b) {
        int n = inv[b * P_ + p];
        if (n >= 0) acc += feat[(size_t)(b * N_ + n) * FEATD_ + d];
    }
    mean_b[(size_t)p * FEATD_ + d] = acc * (1.0f / (float)B_);
}

// ---------------------------------------------------------------------------
// diff_bf16[r][d] = bf16(mean_b[pids[r]][d] - feat[r][d])
// ---------------------------------------------------------------------------
__global__ __launch_bounds__(256) void diff_kernel(
    const float* __restrict__ feat, const float* __restrict__ mean_b,
    const int* __restrict__ pids, __hip_bfloat16* __restrict__ diff)
{
    int r = blockIdx.x;
    int pid = pids[r];
    const float* fr = feat + (size_t)r * FEATD_;
    const float* mr = mean_b + (size_t)pid * FEATD_;
    __hip_bfloat16* dr = diff + (size_t)r * FEATD_;
    for (int d = threadIdx.x; d < FEATD_; d += 256)
        dr[d] = __float2bfloat16(mr[d] - fr[d]);
}

// ---------------------------------------------------------------------------
// fc2: out[bn][o] = h1[bn] . fc2_w[o] + fc2_b[o]
// ---------------------------------------------------------------------------
__global__ __launch_bounds__(256) void fc2_kernel(
    const float* __restrict__ h1, const float* __restrict__ fc2_w,
    const float* __restrict__ fc2_b, float* __restrict__ out)
{
    int bn = blockIdx.x;
    int tid = threadIdx.x;
    __shared__ __align__(16) float row[H1_];
    __shared__ float partial[32][8];
    ((float4*)row)[tid] = ((const float4*)(h1 + (size_t)bn * H1_))[tid];
    __syncthreads();
    int o = tid >> 3, part = tid & 7;
    float acc = 0.0f;
    if (o < O_) {
        const float* wrow = fc2_w + (size_t)o * H1_ + part * 128;
        const float* hrow = row + part * 128;
        #pragma unroll 4
        for (int j = 0; j < 128; ++j) acc += hrow[j] * wrow[j];
    }
    partial[o][part] = acc;
    __syncthreads();
    if (part == 0 && o < O_) {
        float s = fc2_b[o];
        #pragma unroll
        for (int p = 0; p < 8; ++p) s += partial[o][p];
        out[(size_t)bn * O_ + o] = s;
    }
}

// ---------------------------------------------------------------------------
// Launch
// ---------------------------------------------------------------------------
extern "C" void kernel_launch(void* const* d_in, const int* in_sizes, int n_in,
                              void* d_out, int out_size, void* d_ws, size_t ws_size,
                              hipStream_t stream) {
    const float* fmap  = (const float*)d_in[0];
    const float* boxes = (const float*)d_in[1];
    const int*   pids  = (const int*)  d_in[2];
    const float* w1    = (const float*)d_in[3];
    const float* w2    = (const float*)d_in[4];
    const float* fc1_w = (const float*)d_in[5];
    const float* fc1_b = (const float*)d_in[6];
    const float* fc2_w = (const float*)d_in[7];
    const float* fc2_b = (const float*)d_in[8];
    float* out = (float*)d_out;

    // workspace layout (all 16B aligned)
    char* wsb = (char*)d_ws;
    __hip_bfloat16* Wc    = (__hip_bfloat16*)wsb;                       // 256*1024
    __hip_bfloat16* roi   = Wc + 256 * 1024;                            // 9216*1024
    __hip_bfloat16* fc1wp = roi + (size_t)ROWS_ * C_;                   // 1024*2304
    __hip_bfloat16* diffp = fc1wp + (size_t)H1_ * FEATD_;               // 1024*2304
    float* feat   = (float*)(diffp + (size_t)H1_ * FEATD_);             // 1024*2304
    float* mean_b = feat + (size_t)(B_ * N_) * FEATD_;                  // 20*2304
    float* h1     = mean_b + (size_t)P_ * FEATD_;                       // 1024*1024
    int*   inv    = (int*)(h1 + (size_t)(B_ * N_) * H1_);               // 128*20
    float* wpart  = (float*)(inv + 128 * P_ + 64);                      // 8*256*1024
    Tap*   taps   = (Tap*)(wpart + 8 * 256 * 1024);                     // 36864*32B

    hipLaunchKernelGGL(taps_kernel, dim3(144), dim3(256), 0, stream,
                       boxes, taps);
    hipLaunchKernelGGL(wcombine_split_kernel, dim3(16, 4, 8), dim3(256), 0, stream,
                       w1, w2, wpart);
    hipLaunchKernelGGL(wc_reduce_kernel, dim3(1024), dim3(256), 0, stream,
                       wpart, Wc);
    hipLaunchKernelGGL(roi_kernel, dim3(4, 128), dim3(576), 0, stream,
                       fmap, taps, roi);
    hipLaunchKernelGGL(fc1w_perm_kernel, dim3(9, 1024), dim3(256), 0, stream,
                       fc1_w, fc1wp);
    hipLaunchKernelGGL((mfma_gemm_kernel<0>), dim3(4, 144), dim3(256), 0, stream,
                       roi, Wc, (const float*)nullptr, feat, 1024);
    hipLaunchKernelGGL(invmap_kernel, dim3(128), dim3(64), 0, stream,
                       pids, inv);
    hipLaunchKernelGGL(meanb_kernel, dim3(20, 9), dim3(256), 0, stream,
                       feat, inv, mean_b);
    hipLaunchKernelGGL(diff_kernel, dim3(1024), dim3(256), 0, stream,
                       feat, mean_b, pids, diffp);
    hipLaunchKernelGGL((mfma_gemm_kernel<1>), dim3(16, 16), dim3(256), 0, stream,
                       diffp, fc1wp, fc1_b, h1, FEATD_);
    hipLaunchKernelGGL(fc2_kernel, dim3(1024), dim3(256), 0, stream,
                       h1, fc2_w, fc2_b, out);
}

// Round 5
// 327.964 us; speedup vs baseline: 1.2750x; 1.2750x over previous
//
#include <hip/hip_runtime.h>
#include <hip/hip_bf16.h>
#include <cstddef>
#include <cstdint>

// ---------------------------------------------------------------------------
// Problem constants
// ---------------------------------------------------------------------------
#define B_   128
#define N_   8
#define C_   1024
#define FS_  14
#define POS_ 196            // 14*14
#define P_   20
#define HWC_ 9              // 3*3 cells
#define ROWS_ 9216          // B*N*HWC
#define CMID_ 256
#define FEATD_ 2304         // CMID*HWC
#define H1_  1024
#define O_   27

typedef __attribute__((ext_vector_type(8))) short bf16x8;   // 8 bf16 (4 VGPRs)
typedef __attribute__((ext_vector_type(4))) float f32x4;

// async global->LDS, 16B per lane; LDS dest = wave-uniform base + lane*16
__device__ __forceinline__ void gld16(const void* g, void* l) {
    __builtin_amdgcn_global_load_lds(
        (const __attribute__((address_space(1))) unsigned int*)g,
        (__attribute__((address_space(3))) unsigned int*)l, 16, 0, 0);
}

// ---------------------------------------------------------------------------
// Kernel 1a: split-K partials of Wc = w2 @ w1
//   grid (16,4,8), 64x64 tile, K-slice 64 -> 512 blocks (2/CU), fp32
// ---------------------------------------------------------------------------
__global__ __launch_bounds__(256) void wcombine_split_kernel(
    const float* __restrict__ w1,   // (512,1024)
    const float* __restrict__ w2,   // (256,512)
    float* __restrict__ wpart)      // (8,256,1024) fp32
{
    const int tid = threadIdx.x;
    const int tx = tid & 15, ty = tid >> 4;
    const int c0 = blockIdx.x * 64;
    const int o0 = blockIdx.y * 64;
    const int kb = blockIdx.z * 64;
    __shared__ __align__(16) float As[16][68];
    __shared__ __align__(16) float Bs[16][68];
    float acc[4][4] = {};
    for (int k0 = kb; k0 < kb + 64; k0 += 16) {
        for (int i = tid; i < 64 * 16; i += 256) {
            int k = i & 15, m = i >> 4;
            As[k][m] = w2[(size_t)(o0 + m) * 512 + k0 + k];
        }
        for (int i = tid; i < 64 * 16; i += 256) {
            int n = i & 63, k = i >> 6;
            Bs[k][n] = w1[(size_t)(k0 + k) * 1024 + c0 + n];
        }
        __syncthreads();
        #pragma unroll
        for (int k = 0; k < 16; ++k) {
            float4 a = *(const float4*)&As[k][ty * 4];
            float4 b = *(const float4*)&Bs[k][tx * 4];
            float av[4] = {a.x, a.y, a.z, a.w};
            float bv[4] = {b.x, b.y, b.z, b.w};
            #pragma unroll
            for (int i = 0; i < 4; ++i)
                #pragma unroll
                for (int j = 0; j < 4; ++j)
                    acc[i][j] += av[i] * bv[j];
        }
        __syncthreads();
    }
    float* dst = wpart + (size_t)blockIdx.z * (256 * 1024);
    for (int i = 0; i < 4; ++i) {
        float4 v = make_float4(acc[i][0], acc[i][1], acc[i][2], acc[i][3]);
        *(float4*)&dst[(size_t)(o0 + ty * 4 + i) * 1024 + c0 + tx * 4] = v;
    }
}

// ---------------------------------------------------------------------------
// Kernel 1b: Wc = bf16( sum_z wpart[z] )
// ---------------------------------------------------------------------------
__global__ __launch_bounds__(256) void wc_reduce_kernel(
    const float* __restrict__ wpart, __hip_bfloat16* __restrict__ Wc)
{
    int idx = blockIdx.x * 256 + threadIdx.x;
    float s = 0.f;
    #pragma unroll
    for (int z = 0; z < 8; ++z) s += wpart[(size_t)z * (256 * 1024) + idx];
    Wc[idx] = __float2bfloat16(s);
}

// ---------------------------------------------------------------------------
// Kernel 2: ROI align -> roi_bf16 (9216 x 1024), row r=(b*8+n)*9+cell
//   grid (4,128), block 576 = 64 chan-lanes x 9 cells.
//   Taps computed in-register with SEPARABLE y/x weights (computed once per
//   n, combined per tap) — no global tables (round-4 lesson: global tap
//   loads serialize and blow VGPRs; recompute-in-VALU wins here).
// ---------------------------------------------------------------------------
__global__ __launch_bounds__(576) void roi_kernel(
    const float* __restrict__ fmap,   // (128,1024,14,14)
    const float* __restrict__ boxes,  // (128,8,4)
    __hip_bfloat16* __restrict__ roi_mat)
{
    const int b = blockIdx.y;
    const int q = blockIdx.x;
    const int tid = threadIdx.x;
    const int c_local = tid & 63;
    const int cell = tid >> 6;          // 0..8
    const int ch = cell / 3, cw = cell % 3;
    __shared__ float stage[64 * 197];   // stride 197: 2-way max aliasing (free)

    for (int chunk = 0; chunk < 4; ++chunk) {
        const int c0 = q * 256 + chunk * 64;
        __syncthreads();
        const float* src = fmap + (size_t)(b * C_ + c0) * POS_;
        for (int i4 = tid; i4 < (64 * POS_) / 4; i4 += 576) {
            float4 v = ((const float4*)src)[i4];
            int base = i4 * 4;
            int c = base / POS_;
            int pos = base - c * POS_;
            float* dst = &stage[c * 197 + pos];
            dst[0] = v.x; dst[1] = v.y; dst[2] = v.z; dst[3] = v.w;
        }
        __syncthreads();

        const float* ch_ptr = &stage[c_local * 197];
        for (int n = 0; n < N_; ++n) {
            float4 bx = *(const float4*)(boxes + (size_t)(b * N_ + n) * 4);
            float bw = (bx.z - bx.x) * (1.0f / 3.0f);
            float bh = (bx.w - bx.y) * (1.0f / 3.0f);

            // y side (2 samples for this cell row)
            float ywh[2], ywl[2];          // hy, ly per sample
            int   yoA[2], yoB[2];          // row offsets y0*14, y1*14
            bool  vy[2];
            #pragma unroll
            for (int si = 0; si < 2; ++si) {
                float yy = bx.y + ((float)(2 * ch + si) + 0.5f) * 0.5f * bh;
                vy[si] = (yy > -1.0f) && (yy < (float)FS_);
                float y = fminf(fmaxf(yy, 0.0f), (float)(FS_ - 1));
                int y0 = (int)floorf(y);
                float ly = y - (float)y0;
                ywh[si] = 1.0f - ly;
                ywl[si] = ly;
                yoA[si] = y0 * FS_;
                yoB[si] = min(y0 + 1, FS_ - 1) * FS_;
            }
            // x side (2 samples for this cell col)
            float xwh[2], xwl[2];
            int   xo[2];
            bool  vx[2];
            #pragma unroll
            for (int sj = 0; sj < 2; ++sj) {
                float xx = bx.x + ((float)(2 * cw + sj) + 0.5f) * 0.5f * bw;
                vx[sj] = (xx > -1.0f) && (xx < (float)FS_);
                float x = fminf(fmaxf(xx, 0.0f), (float)(FS_ - 1));
                int x0 = (int)floorf(x);
                float lx = x - (float)x0;
                xwh[sj] = 1.0f - lx;
                xwl[sj] = lx;
                xo[sj] = x0;   // pair (x0, x0+1); lx=0 at x0=13 so +1 read is weight-0
            }

            float acc = 0.0f;
            #pragma unroll
            for (int si = 0; si < 2; ++si) {
                #pragma unroll
                for (int sj = 0; sj < 2; ++sj) {
                    float s = (vy[si] && vx[sj]) ? 0.25f : 0.0f;
                    const float* pa = ch_ptr + yoA[si] + xo[sj];
                    const float* pb = ch_ptr + yoB[si] + xo[sj];
                    float t0 = xwh[sj] * pa[0] + xwl[sj] * pa[1];
                    float t1 = xwh[sj] * pb[0] + xwl[sj] * pb[1];
                    acc += s * (ywh[si] * t0 + ywl[si] * t1);
                }
            }
            roi_mat[(size_t)((b * N_ + n) * HWC_ + cell) * C_ + c0 + c_local] =
                __float2bfloat16(acc);
        }
    }
}

// ---------------------------------------------------------------------------
// MFMA GEMM: C = A(M x K) @ B(N x K)^T, A/B bf16 K-contiguous rows.
// 64x64 tile, BK=64, 4 waves in 2x2, each wave 2x2 of 16x16x32 MFMA.
// XOR-swizzled LDS realized by permuting the per-lane GLOBAL source address.
// EPI 0: scatter to feat[bn*2304 + hw*256 + o]; EPI 1: bias+relu -> h1.
// ---------------------------------------------------------------------------
template<int EPI>
__global__ __launch_bounds__(256) void mfma_gemm_kernel(
    const __hip_bfloat16* __restrict__ A,
    const __hip_bfloat16* __restrict__ Bm,
    const float* __restrict__ bias,
    float* __restrict__ C, int K)
{
    const int tid = threadIdx.x;
    const int wave = tid >> 6, lane = tid & 63;
    const int r0 = blockIdx.y * 64, n0 = blockIdx.x * 64;
    const int wm = (wave >> 1) * 32, wn = (wave & 1) * 32;
    const int m16 = lane & 15, quad = lane >> 4;
    __shared__ __align__(16) __hip_bfloat16 As[64 * 64];
    __shared__ __align__(16) __hip_bfloat16 Bs[64 * 64];

    f32x4 acc[2][2];
    #pragma unroll
    for (int i = 0; i < 2; ++i)
        #pragma unroll
        for (int j = 0; j < 2; ++j)
            acc[i][j] = (f32x4){0.f, 0.f, 0.f, 0.f};

    const int s0 = wave * 64 + lane;
    const int ms0 = s0 >> 3, cs0 = (s0 & 7) ^ (ms0 & 7);
    const int s1 = 256 + s0;
    const int ms1 = s1 >> 3, cs1 = (s1 & 7) ^ (ms1 & 7);
    const size_t rA0 = (size_t)(r0 + ms0) * K + cs0 * 8;
    const size_t rA1 = (size_t)(r0 + ms1) * K + cs1 * 8;
    const size_t rB0 = (size_t)(n0 + ms0) * K + cs0 * 8;
    const size_t rB1 = (size_t)(n0 + ms1) * K + cs1 * 8;

    for (int k0 = 0; k0 < K; k0 += 64) {
        gld16(A + rA0 + k0, &As[wave * 512]);
        gld16(Bm + rB0 + k0, &Bs[wave * 512]);
        gld16(A + rA1 + k0, &As[2048 + wave * 512]);
        gld16(Bm + rB1 + k0, &Bs[2048 + wave * 512]);
        __syncthreads();
        #pragma unroll
        for (int ks = 0; ks < 2; ++ks) {
            bf16x8 af[2], bfv[2];
            #pragma unroll
            for (int t = 0; t < 2; ++t) {
                int m = wm + t * 16 + m16;
                int cp = (ks * 4 + quad) ^ (m & 7);
                af[t] = *(const bf16x8*)&As[(m * 8 + cp) * 8];
                int n = wn + t * 16 + m16;
                int cq = (ks * 4 + quad) ^ (n & 7);
                bfv[t] = *(const bf16x8*)&Bs[(n * 8 + cq) * 8];
            }
            #pragma unroll
            for (int i = 0; i < 2; ++i)
                #pragma unroll
                for (int j = 0; j < 2; ++j)
                    acc[i][j] = __builtin_amdgcn_mfma_f32_16x16x32_bf16(
                        af[i], bfv[j], acc[i][j], 0, 0, 0);
        }
        __syncthreads();
    }

    // C/D layout: col = lane&15, row = quad*4 + reg
    #pragma unroll
    for (int i = 0; i < 2; ++i) {
        #pragma unroll
        for (int j = 0; j < 2; ++j) {
            int col = n0 + wn + j * 16 + m16;
            int rbase = r0 + wm + i * 16 + quad * 4;
            if (EPI == 0) {
                #pragma unroll
                for (int g = 0; g < 4; ++g) {
                    int r = rbase + g;
                    int bn = r / 9, hw = r - bn * 9;
                    C[(size_t)bn * FEATD_ + hw * 256 + col] = acc[i][j][g];
                }
            } else {
                float bv = bias[col];
                #pragma unroll
                for (int g = 0; g < 4; ++g) {
                    int r = rbase + g;
                    float v = acc[i][j][g] + bv;
                    C[(size_t)r * H1_ + col] = v > 0.f ? v : 0.f;
                }
            }
        }
    }
}

// ---------------------------------------------------------------------------
// fc1_w (1024 x 2304 fp32, k = o*9+hw) -> bf16 permuted (k' = hw*256+o)
// ---------------------------------------------------------------------------
__global__ __launch_bounds__(256) void fc1w_perm_kernel(
    const float* __restrict__ src, __hip_bfloat16* __restrict__ dst)
{
    int h = blockIdx.y;
    int d2 = blockIdx.x * 256 + threadIdx.x;   // hw*256+o
    int hw = d2 >> 8, o = d2 & 255;
    dst[(size_t)h * FEATD_ + d2] =
        __float2bfloat16(src[(size_t)h * FEATD_ + o * HWC_ + hw]);
}

// ---------------------------------------------------------------------------
// inv[b][p] = n with pids[b][n]==p else -1
// ---------------------------------------------------------------------------
__global__ __launch_bounds__(64) void invmap_kernel(
    const int* __restrict__ pids, int* __restrict__ inv)
{
    int b = blockIdx.x;
    int p = threadIdx.x;
    if (p < P_) {
        int v = -1;
        for (int n = 0; n < N_; ++n)
            if (pids[b * N_ + n] == p) v = n;
        inv[b * P_ + p] = v;
    }
}

// ---------------------------------------------------------------------------
// mean_b[p][d] = (1/128) sum_b feat[b, inv[b][p], d]
// ---------------------------------------------------------------------------
__global__ __launch_bounds__(256) void meanb_kernel(
    const float* __restrict__ feat, const int* __restrict__ inv,
    float* __restrict__ mean_b)
{
    int p = blockIdx.x;
    int d = blockIdx.y * 256 + threadIdx.x;
    float acc = 0.0f;
    for (int b = 0; b < B_; ++b) {
        int n = inv[b * P_ + p];
        if (n >= 0) acc += feat[(size_t)(b * N_ + n) * FEATD_ + d];
    }
    mean_b[(size_t)p * FEATD_ + d] = acc * (1.0f / (float)B_);
}

// ---------------------------------------------------------------------------
// diff_bf16[r][d] = bf16(mean_b[pids[r]][d] - feat[r][d])
// ---------------------------------------------------------------------------
__global__ __launch_bounds__(256) void diff_kernel(
    const float* __restrict__ feat, const float* __restrict__ mean_b,
    const int* __restrict__ pids, __hip_bfloat16* __restrict__ diff)
{
    int r = blockIdx.x;
    int pid = pids[r];
    const float* fr = feat + (size_t)r * FEATD_;
    const float* mr = mean_b + (size_t)pid * FEATD_;
    __hip_bfloat16* dr = diff + (size_t)r * FEATD_;
    for (int d = threadIdx.x; d < FEATD_; d += 256)
        dr[d] = __float2bfloat16(mr[d] - fr[d]);
}

// ---------------------------------------------------------------------------
// fc2: out[bn][o] = h1[bn] . fc2_w[o] + fc2_b[o]
// ---------------------------------------------------------------------------
__global__ __launch_bounds__(256) void fc2_kernel(
    const float* __restrict__ h1, const float* __restrict__ fc2_w,
    const float* __restrict__ fc2_b, float* __restrict__ out)
{
    int bn = blockIdx.x;
    int tid = threadIdx.x;
    __shared__ __align__(16) float row[H1_];
    __shared__ float partial[32][8];
    ((float4*)row)[tid] = ((const float4*)(h1 + (size_t)bn * H1_))[tid];
    __syncthreads();
    int o = tid >> 3, part = tid & 7;
    float acc = 0.0f;
    if (o < O_) {
        const float* wrow = fc2_w + (size_t)o * H1_ + part * 128;
        const float* hrow = row + part * 128;
        #pragma unroll 4
        for (int j = 0; j < 128; ++j) acc += hrow[j] * wrow[j];
    }
    partial[o][part] = acc;
    __syncthreads();
    if (part == 0 && o < O_) {
        float s = fc2_b[o];
        #pragma unroll
        for (int p = 0; p < 8; ++p) s += partial[o][p];
        out[(size_t)bn * O_ + o] = s;
    }
}

// ---------------------------------------------------------------------------
// Launch
// ---------------------------------------------------------------------------
extern "C" void kernel_launch(void* const* d_in, const int* in_sizes, int n_in,
                              void* d_out, int out_size, void* d_ws, size_t ws_size,
                              hipStream_t stream) {
    const float* fmap  = (const float*)d_in[0];
    const float* boxes = (const float*)d_in[1];
    const int*   pids  = (const int*)  d_in[2];
    const float* w1    = (const float*)d_in[3];
    const float* w2    = (const float*)d_in[4];
    const float* fc1_w = (const float*)d_in[5];
    const float* fc1_b = (const float*)d_in[6];
    const float* fc2_w = (const float*)d_in[7];
    const float* fc2_b = (const float*)d_in[8];
    float* out = (float*)d_out;

    // workspace layout (all 16B aligned)
    char* wsb = (char*)d_ws;
    __hip_bfloat16* Wc    = (__hip_bfloat16*)wsb;                       // 256*1024
    __hip_bfloat16* roi   = Wc + 256 * 1024;                            // 9216*1024
    __hip_bfloat16* fc1wp = roi + (size_t)ROWS_ * C_;                   // 1024*2304
    __hip_bfloat16* diffp = fc1wp + (size_t)H1_ * FEATD_;               // 1024*2304
    float* feat   = (float*)(diffp + (size_t)H1_ * FEATD_);             // 1024*2304
    float* mean_b = feat + (size_t)(B_ * N_) * FEATD_;                  // 20*2304
    float* h1     = mean_b + (size_t)P_ * FEATD_;                       // 1024*1024
    int*   inv    = (int*)(h1 + (size_t)(B_ * N_) * H1_);               // 128*20
    float* wpart  = (float*)(inv + 128 * P_ + 64);                      // 8*256*1024

    hipLaunchKernelGGL(wcombine_split_kernel, dim3(16, 4, 8), dim3(256), 0, stream,
                       w1, w2, wpart);
    hipLaunchKernelGGL(wc_reduce_kernel, dim3(1024), dim3(256), 0, stream,
                       wpart, Wc);
    hipLaunchKernelGGL(roi_kernel, dim3(4, 128), dim3(576), 0, stream,
                       fmap, boxes, roi);
    hipLaunchKernelGGL(fc1w_perm_kernel, dim3(9, 1024), dim3(256), 0, stream,
                       fc1_w, fc1wp);
    hipLaunchKernelGGL((mfma_gemm_kernel<0>), dim3(4, 144), dim3(256), 0, stream,
                       roi, Wc, (const float*)nullptr, feat, 1024);
    hipLaunchKernelGGL(invmap_kernel, dim3(128), dim3(64), 0, stream,
                       pids, inv);
    hipLaunchKernelGGL(meanb_kernel, dim3(20, 9), dim3(256), 0, stream,
                       feat, inv, mean_b);
    hipLaunchKernelGGL(diff_kernel, dim3(1024), dim3(256), 0, stream,
                       feat, mean_b, pids, diffp);
    hipLaunchKernelGGL((mfma_gemm_kernel<1>), dim3(16, 16), dim3(256), 0, stream,
                       diffp, fc1wp, fc1_b, h1, FEATD_);
    hipLaunchKernelGGL(fc2_kernel, dim3(1024), dim3(256), 0, stream,
                       h1, fc2_w, fc2_b, out);
}

// Round 6
// 313.168 us; speedup vs baseline: 1.3353x; 1.0472x over previous
//
#include <hip/hip_runtime.h>
#include <hip/hip_bf16.h>
#include <cstddef>
#include <cstdint>

// ---------------------------------------------------------------------------
// Problem constants
// ---------------------------------------------------------------------------
#define B_   128
#define N_   8
#define C_   1024
#define FS_  14
#define POS_ 196            // 14*14
#define P_   20
#define HWC_ 9              // 3*3 cells
#define ROWS_ 9216          // B*N*HWC
#define CMID_ 256
#define FEATD_ 2304         // CMID*HWC
#define H1_  1024
#define O_   27

typedef __attribute__((ext_vector_type(8))) short bf16x8;   // 8 bf16 (4 VGPRs)
typedef __attribute__((ext_vector_type(4))) float f32x4;

// async global->LDS, 16B per lane; LDS dest = wave-uniform base + lane*16
__device__ __forceinline__ void gld16(const void* g, void* l) {
    __builtin_amdgcn_global_load_lds(
        (const __attribute__((address_space(1))) unsigned int*)g,
        (__attribute__((address_space(3))) unsigned int*)l, 16, 0, 0);
}

// ---------------------------------------------------------------------------
// Kernel 1a: split-K partials of Wc = w2 @ w1
//   grid (16,4,8), 64x64 tile, K-slice 64 -> 512 blocks (2/CU), fp32
// ---------------------------------------------------------------------------
__global__ __launch_bounds__(256) void wcombine_split_kernel(
    const float* __restrict__ w1,   // (512,1024)
    const float* __restrict__ w2,   // (256,512)
    float* __restrict__ wpart)      // (8,256,1024) fp32
{
    const int tid = threadIdx.x;
    const int tx = tid & 15, ty = tid >> 4;
    const int c0 = blockIdx.x * 64;
    const int o0 = blockIdx.y * 64;
    const int kb = blockIdx.z * 64;
    __shared__ __align__(16) float As[16][68];
    __shared__ __align__(16) float Bs[16][68];
    float acc[4][4] = {};
    for (int k0 = kb; k0 < kb + 64; k0 += 16) {
        for (int i = tid; i < 64 * 16; i += 256) {
            int k = i & 15, m = i >> 4;
            As[k][m] = w2[(size_t)(o0 + m) * 512 + k0 + k];
        }
        for (int i = tid; i < 64 * 16; i += 256) {
            int n = i & 63, k = i >> 6;
            Bs[k][n] = w1[(size_t)(k0 + k) * 1024 + c0 + n];
        }
        __syncthreads();
        #pragma unroll
        for (int k = 0; k < 16; ++k) {
            float4 a = *(const float4*)&As[k][ty * 4];
            float4 b = *(const float4*)&Bs[k][tx * 4];
            float av[4] = {a.x, a.y, a.z, a.w};
            float bv[4] = {b.x, b.y, b.z, b.w};
            #pragma unroll
            for (int i = 0; i < 4; ++i)
                #pragma unroll
                for (int j = 0; j < 4; ++j)
                    acc[i][j] += av[i] * bv[j];
        }
        __syncthreads();
    }
    float* dst = wpart + (size_t)blockIdx.z * (256 * 1024);
    for (int i = 0; i < 4; ++i) {
        float4 v = make_float4(acc[i][0], acc[i][1], acc[i][2], acc[i][3]);
        *(float4*)&dst[(size_t)(o0 + ty * 4 + i) * 1024 + c0 + tx * 4] = v;
    }
}

// ---------------------------------------------------------------------------
// Kernel 1b: Wc = bf16( sum_z wpart[z] )
// ---------------------------------------------------------------------------
__global__ __launch_bounds__(256) void wc_reduce_kernel(
    const float* __restrict__ wpart, __hip_bfloat16* __restrict__ Wc)
{
    int idx = blockIdx.x * 256 + threadIdx.x;
    float s = 0.f;
    #pragma unroll
    for (int z = 0; z < 8; ++z) s += wpart[(size_t)z * (256 * 1024) + idx];
    Wc[idx] = __float2bfloat16(s);
}

// ---------------------------------------------------------------------------
// Kernel 2: ROI align -> roi_bf16 (9216 x 1024), row r=(b*8+n)*9+cell
//   grid (16 chunks, 128 batches): ONE 64-channel chunk per block (2048
//   blocks) — the r3 serial 4-chunk loop split across the grid so staging
//   and compute phases of independent blocks overlap on each CU.
//   Inner tap math = exact r3 form (r4/r5 lessons: global tap tables and
//   separable precompute both regress; recompute-per-tap pipelines best).
// ---------------------------------------------------------------------------
__global__ __launch_bounds__(576) void roi_kernel(
    const float* __restrict__ fmap,   // (128,1024,14,14)
    const float* __restrict__ boxes,  // (128,8,4)
    __hip_bfloat16* __restrict__ roi_mat)
{
    const int b = blockIdx.y;
    const int c0 = blockIdx.x * 64;
    const int tid = threadIdx.x;
    const int c_local = tid & 63;
    const int cell = tid >> 6;          // 0..8
    const int ch = cell / 3, cw = cell % 3;
    __shared__ float stage[64 * 197];   // stride 197: 2-way max aliasing (free)

    const float* src = fmap + (size_t)(b * C_ + c0) * POS_;
    for (int i4 = tid; i4 < (64 * POS_) / 4; i4 += 576) {
        float4 v = ((const float4*)src)[i4];
        int base = i4 * 4;
        int c = base / POS_;
        int pos = base - c * POS_;
        float* dst = &stage[c * 197 + pos];
        dst[0] = v.x; dst[1] = v.y; dst[2] = v.z; dst[3] = v.w;
    }
    __syncthreads();

    const float* ch_ptr = &stage[c_local * 197];
    for (int n = 0; n < N_; ++n) {
        const float* bx = boxes + (size_t)(b * N_ + n) * 4;
        float x1 = bx[0], y1 = bx[1], x2 = bx[2], y2 = bx[3];
        float bw = (x2 - x1) * (1.0f / 3.0f);
        float bh = (y2 - y1) * (1.0f / 3.0f);
        float acc = 0.0f;
        #pragma unroll
        for (int si = 0; si < 2; ++si) {
            float yy = y1 + ((float)(2 * ch + si) + 0.5f) * 0.5f * bh;
            #pragma unroll
            for (int sj = 0; sj < 2; ++sj) {
                float xx = x1 + ((float)(2 * cw + sj) + 0.5f) * 0.5f * bw;
                bool valid = (yy > -1.0f) && (yy < (float)FS_) &&
                             (xx > -1.0f) && (xx < (float)FS_);
                float y = fminf(fmaxf(yy, 0.0f), (float)(FS_ - 1));
                float x = fminf(fmaxf(xx, 0.0f), (float)(FS_ - 1));
                int y0 = (int)floorf(y);
                int x0 = (int)floorf(x);
                int y1i = min(y0 + 1, FS_ - 1);
                int x1i = min(x0 + 1, FS_ - 1);
                float ly = y - (float)y0, lx = x - (float)x0;
                float hy = 1.0f - ly,     hx = 1.0f - lx;
                float v00 = ch_ptr[y0 * FS_ + x0];
                float v01 = ch_ptr[y0 * FS_ + x1i];
                float v10 = ch_ptr[y1i * FS_ + x0];
                float v11 = ch_ptr[y1i * FS_ + x1i];
                float val = hy * hx * v00 + hy * lx * v01 +
                            ly * hx * v10 + ly * lx * v11;
                acc += valid ? val : 0.0f;
            }
        }
        roi_mat[(size_t)((b * N_ + n) * HWC_ + cell) * C_ + c0 + c_local] =
            __float2bfloat16(acc * 0.25f);
    }
}

// ---------------------------------------------------------------------------
// MFMA GEMM: C = A(M x K) @ B(N x K)^T, A/B bf16 K-contiguous rows.
// 64x64 tile, BK=64, 4 waves in 2x2, each wave 2x2 of 16x16x32 MFMA.
// XOR-swizzled LDS realized by permuting the per-lane GLOBAL source address.
// EPI 0: scatter to feat[bn*2304 + hw*256 + o]; EPI 1: bias+relu -> h1.
// ---------------------------------------------------------------------------
template<int EPI>
__global__ __launch_bounds__(256) void mfma_gemm_kernel(
    const __hip_bfloat16* __restrict__ A,
    const __hip_bfloat16* __restrict__ Bm,
    const float* __restrict__ bias,
    float* __restrict__ C, int K)
{
    const int tid = threadIdx.x;
    const int wave = tid >> 6, lane = tid & 63;
    const int r0 = blockIdx.y * 64, n0 = blockIdx.x * 64;
    const int wm = (wave >> 1) * 32, wn = (wave & 1) * 32;
    const int m16 = lane & 15, quad = lane >> 4;
    __shared__ __align__(16) __hip_bfloat16 As[64 * 64];
    __shared__ __align__(16) __hip_bfloat16 Bs[64 * 64];

    f32x4 acc[2][2];
    #pragma unroll
    for (int i = 0; i < 2; ++i)
        #pragma unroll
        for (int j = 0; j < 2; ++j)
            acc[i][j] = (f32x4){0.f, 0.f, 0.f, 0.f};

    const int s0 = wave * 64 + lane;
    const int ms0 = s0 >> 3, cs0 = (s0 & 7) ^ (ms0 & 7);
    const int s1 = 256 + s0;
    const int ms1 = s1 >> 3, cs1 = (s1 & 7) ^ (ms1 & 7);
    const size_t rA0 = (size_t)(r0 + ms0) * K + cs0 * 8;
    const size_t rA1 = (size_t)(r0 + ms1) * K + cs1 * 8;
    const size_t rB0 = (size_t)(n0 + ms0) * K + cs0 * 8;
    const size_t rB1 = (size_t)(n0 + ms1) * K + cs1 * 8;

    for (int k0 = 0; k0 < K; k0 += 64) {
        gld16(A + rA0 + k0, &As[wave * 512]);
        gld16(Bm + rB0 + k0, &Bs[wave * 512]);
        gld16(A + rA1 + k0, &As[2048 + wave * 512]);
        gld16(Bm + rB1 + k0, &Bs[2048 + wave * 512]);
        __syncthreads();
        #pragma unroll
        for (int ks = 0; ks < 2; ++ks) {
            bf16x8 af[2], bfv[2];
            #pragma unroll
            for (int t = 0; t < 2; ++t) {
                int m = wm + t * 16 + m16;
                int cp = (ks * 4 + quad) ^ (m & 7);
                af[t] = *(const bf16x8*)&As[(m * 8 + cp) * 8];
                int n = wn + t * 16 + m16;
                int cq = (ks * 4 + quad) ^ (n & 7);
                bfv[t] = *(const bf16x8*)&Bs[(n * 8 + cq) * 8];
            }
            #pragma unroll
            for (int i = 0; i < 2; ++i)
                #pragma unroll
                for (int j = 0; j < 2; ++j)
                    acc[i][j] = __builtin_amdgcn_mfma_f32_16x16x32_bf16(
                        af[i], bfv[j], acc[i][j], 0, 0, 0);
        }
        __syncthreads();
    }

    // C/D layout: col = lane&15, row = quad*4 + reg
    #pragma unroll
    for (int i = 0; i < 2; ++i) {
        #pragma unroll
        for (int j = 0; j < 2; ++j) {
            int col = n0 + wn + j * 16 + m16;
            int rbase = r0 + wm + i * 16 + quad * 4;
            if (EPI == 0) {
                #pragma unroll
                for (int g = 0; g < 4; ++g) {
                    int r = rbase + g;
                    int bn = r / 9, hw = r - bn * 9;
                    C[(size_t)bn * FEATD_ + hw * 256 + col] = acc[i][j][g];
                }
            } else {
                float bv = bias[col];
                #pragma unroll
                for (int g = 0; g < 4; ++g) {
                    int r = rbase + g;
                    float v = acc[i][j][g] + bv;
                    C[(size_t)r * H1_ + col] = v > 0.f ? v : 0.f;
                }
            }
        }
    }
}

// ---------------------------------------------------------------------------
// fc1_w (1024 x 2304 fp32, k = o*9+hw) -> bf16 permuted (k' = hw*256+o)
// ---------------------------------------------------------------------------
__global__ __launch_bounds__(256) void fc1w_perm_kernel(
    const float* __restrict__ src, __hip_bfloat16* __restrict__ dst)
{
    int h = blockIdx.y;
    int d2 = blockIdx.x * 256 + threadIdx.x;   // hw*256+o
    int hw = d2 >> 8, o = d2 & 255;
    dst[(size_t)h * FEATD_ + d2] =
        __float2bfloat16(src[(size_t)h * FEATD_ + o * HWC_ + hw]);
}

// ---------------------------------------------------------------------------
// inv[b][p] = n with pids[b][n]==p else -1
// ---------------------------------------------------------------------------
__global__ __launch_bounds__(64) void invmap_kernel(
    const int* __restrict__ pids, int* __restrict__ inv)
{
    int b = blockIdx.x;
    int p = threadIdx.x;
    if (p < P_) {
        int v = -1;
        for (int n = 0; n < N_; ++n)
            if (pids[b * N_ + n] == p) v = n;
        inv[b * P_ + p] = v;
    }
}

// ---------------------------------------------------------------------------
// mean_b[p][d] = (1/128) sum_b feat[b, inv[b][p], d]
// ---------------------------------------------------------------------------
__global__ __launch_bounds__(256) void meanb_kernel(
    const float* __restrict__ feat, const int* __restrict__ inv,
    float* __restrict__ mean_b)
{
    int p = blockIdx.x;
    int d = blockIdx.y * 256 + threadIdx.x;
    float acc = 0.0f;
    for (int b = 0; b < B_; ++b) {
        int n = inv[b * P_ + p];
        if (n >= 0) acc += feat[(size_t)(b * N_ + n) * FEATD_ + d];
    }
    mean_b[(size_t)p * FEATD_ + d] = acc * (1.0f / (float)B_);
}

// ---------------------------------------------------------------------------
// diff_bf16[r][d] = bf16(mean_b[pids[r]][d] - feat[r][d])
// ---------------------------------------------------------------------------
__global__ __launch_bounds__(256) void diff_kernel(
    const float* __restrict__ feat, const float* __restrict__ mean_b,
    const int* __restrict__ pids, __hip_bfloat16* __restrict__ diff)
{
    int r = blockIdx.x;
    int pid = pids[r];
    const float* fr = feat + (size_t)r * FEATD_;
    const float* mr = mean_b + (size_t)pid * FEATD_;
    __hip_bfloat16* dr = diff + (size_t)r * FEATD_;
    for (int d = threadIdx.x; d < FEATD_; d += 256)
        dr[d] = __float2bfloat16(mr[d] - fr[d]);
}

// ---------------------------------------------------------------------------
// fc2: out[bn][o] = h1[bn] . fc2_w[o] + fc2_b[o]
// ---------------------------------------------------------------------------
__global__ __launch_bounds__(256) void fc2_kernel(
    const float* __restrict__ h1, const float* __restrict__ fc2_w,
    const float* __restrict__ fc2_b, float* __restrict__ out)
{
    int bn = blockIdx.x;
    int tid = threadIdx.x;
    __shared__ __align__(16) float row[H1_];
    __shared__ float partial[32][8];
    ((float4*)row)[tid] = ((const float4*)(h1 + (size_t)bn * H1_))[tid];
    __syncthreads();
    int o = tid >> 3, part = tid & 7;
    float acc = 0.0f;
    if (o < O_) {
        const float* wrow = fc2_w + (size_t)o * H1_ + part * 128;
        const float* hrow = row + part * 128;
        #pragma unroll 4
        for (int j = 0; j < 128; ++j) acc += hrow[j] * wrow[j];
    }
    partial[o][part] = acc;
    __syncthreads();
    if (part == 0 && o < O_) {
        float s = fc2_b[o];
        #pragma unroll
        for (int p = 0; p < 8; ++p) s += partial[o][p];
        out[(size_t)bn * O_ + o] = s;
    }
}

// ---------------------------------------------------------------------------
// Launch
// ---------------------------------------------------------------------------
extern "C" void kernel_launch(void* const* d_in, const int* in_sizes, int n_in,
                              void* d_out, int out_size, void* d_ws, size_t ws_size,
                              hipStream_t stream) {
    const float* fmap  = (const float*)d_in[0];
    const float* boxes = (const float*)d_in[1];
    const int*   pids  = (const int*)  d_in[2];
    const float* w1    = (const float*)d_in[3];
    const float* w2    = (const float*)d_in[4];
    const float* fc1_w = (const float*)d_in[5];
    const float* fc1_b = (const float*)d_in[6];
    const float* fc2_w = (const float*)d_in[7];
    const float* fc2_b = (const float*)d_in[8];
    float* out = (float*)d_out;

    // workspace layout (all 16B aligned)
    char* wsb = (char*)d_ws;
    __hip_bfloat16* Wc    = (__hip_bfloat16*)wsb;                       // 256*1024
    __hip_bfloat16* roi   = Wc + 256 * 1024;                            // 9216*1024
    __hip_bfloat16* fc1wp = roi + (size_t)ROWS_ * C_;                   // 1024*2304
    __hip_bfloat16* diffp = fc1wp + (size_t)H1_ * FEATD_;               // 1024*2304
    float* feat   = (float*)(diffp + (size_t)H1_ * FEATD_);             // 1024*2304
    float* mean_b = feat + (size_t)(B_ * N_) * FEATD_;                  // 20*2304
    float* h1     = mean_b + (size_t)P_ * FEATD_;                       // 1024*1024
    int*   inv    = (int*)(h1 + (size_t)(B_ * N_) * H1_);               // 128*20
    float* wpart  = (float*)(inv + 128 * P_ + 64);                      // 8*256*1024

    hipLaunchKernelGGL(wcombine_split_kernel, dim3(16, 4, 8), dim3(256), 0, stream,
                       w1, w2, wpart);
    hipLaunchKernelGGL(wc_reduce_kernel, dim3(1024), dim3(256), 0, stream,
                       wpart, Wc);
    hipLaunchKernelGGL(roi_kernel, dim3(16, 128), dim3(576), 0, stream,
                       fmap, boxes, roi);
    hipLaunchKernelGGL(fc1w_perm_kernel, dim3(9, 1024), dim3(256), 0, stream,
                       fc1_w, fc1wp);
    hipLaunchKernelGGL((mfma_gemm_kernel<0>), dim3(4, 144), dim3(256), 0, stream,
                       roi, Wc, (const float*)nullptr, feat, 1024);
    hipLaunchKernelGGL(invmap_kernel, dim3(128), dim3(64), 0, stream,
                       pids, inv);
    hipLaunchKernelGGL(meanb_kernel, dim3(20, 9), dim3(256), 0, stream,
                       feat, inv, mean_b);
    hipLaunchKernelGGL(diff_kernel, dim3(1024), dim3(256), 0, stream,
                       feat, mean_b, pids, diffp);
    hipLaunchKernelGGL((mfma_gemm_kernel<1>), dim3(16, 16), dim3(256), 0, stream,
                       diffp, fc1wp, fc1_b, h1, FEATD_);
    hipLaunchKernelGGL(fc2_kernel, dim3(1024), dim3(256), 0, stream,
                       h1, fc2_w, fc2_b, out);
}

// Round 7
// 307.856 us; speedup vs baseline: 1.3583x; 1.0173x over previous
//
#include <hip/hip_runtime.h>
#include <hip/hip_bf16.h>
#include <cstddef>
#include <cstdint>

// ---------------------------------------------------------------------------
// Problem constants
// ---------------------------------------------------------------------------
#define B_   128
#define N_   8
#define C_   1024
#define FS_  14
#define POS_ 196            // 14*14
#define P_   20
#define HWC_ 9              // 3*3 cells
#define CMID_ 256
#define FEATD_ 2304         // CMID*HWC
#define H1_  1024
#define O_   27
#define GROWS_ (B_*POS_)    // 25088

typedef __attribute__((ext_vector_type(8))) short bf16x8;   // 8 bf16 (4 VGPRs)
typedef __attribute__((ext_vector_type(4))) float f32x4;

// async global->LDS, 16B per lane; LDS dest = wave-uniform base + lane*16
__device__ __forceinline__ void gld16(const void* g, void* l) {
    __builtin_amdgcn_global_load_lds(
        (const __attribute__((address_space(1))) unsigned int*)g,
        (__attribute__((address_space(3))) unsigned int*)l, 16, 0, 0);
}

// ---------------------------------------------------------------------------
// Kernel 1a: split-K partials of Wc = w2 @ w1
//   grid (16,4,8), 64x64 tile, K-slice 64 -> 512 blocks (2/CU), fp32
// ---------------------------------------------------------------------------
__global__ __launch_bounds__(256) void wcombine_split_kernel(
    const float* __restrict__ w1,   // (512,1024)
    const float* __restrict__ w2,   // (256,512)
    float* __restrict__ wpart)      // (8,256,1024) fp32
{
    const int tid = threadIdx.x;
    const int tx = tid & 15, ty = tid >> 4;
    const int c0 = blockIdx.x * 64;
    const int o0 = blockIdx.y * 64;
    const int kb = blockIdx.z * 64;
    __shared__ __align__(16) float As[16][68];
    __shared__ __align__(16) float Bs[16][68];
    float acc[4][4] = {};
    for (int k0 = kb; k0 < kb + 64; k0 += 16) {
        for (int i = tid; i < 64 * 16; i += 256) {
            int k = i & 15, m = i >> 4;
            As[k][m] = w2[(size_t)(o0 + m) * 512 + k0 + k];
        }
        for (int i = tid; i < 64 * 16; i += 256) {
            int n = i & 63, k = i >> 6;
            Bs[k][n] = w1[(size_t)(k0 + k) * 1024 + c0 + n];
        }
        __syncthreads();
        #pragma unroll
        for (int k = 0; k < 16; ++k) {
            float4 a = *(const float4*)&As[k][ty * 4];
            float4 b = *(const float4*)&Bs[k][tx * 4];
            float av[4] = {a.x, a.y, a.z, a.w};
            float bv[4] = {b.x, b.y, b.z, b.w};
            #pragma unroll
            for (int i = 0; i < 4; ++i)
                #pragma unroll
                for (int j = 0; j < 4; ++j)
                    acc[i][j] += av[i] * bv[j];
        }
        __syncthreads();
    }
    float* dst = wpart + (size_t)blockIdx.z * (256 * 1024);
    for (int i = 0; i < 4; ++i) {
        float4 v = make_float4(acc[i][0], acc[i][1], acc[i][2], acc[i][3]);
        *(float4*)&dst[(size_t)(o0 + ty * 4 + i) * 1024 + c0 + tx * 4] = v;
    }
}

// ---------------------------------------------------------------------------
// Kernel 1b: Wc = bf16( sum_z wpart[z] )
// ---------------------------------------------------------------------------
__global__ __launch_bounds__(256) void wc_reduce_kernel(
    const float* __restrict__ wpart, __hip_bfloat16* __restrict__ Wc)
{
    int idx = blockIdx.x * 256 + threadIdx.x;
    float s = 0.f;
    #pragma unroll
    for (int z = 0; z < 8; ++z) s += wpart[(size_t)z * (256 * 1024) + idx];
    Wc[idx] = __float2bfloat16(s);
}

// ---------------------------------------------------------------------------
// Kernel 2: posgemm — G[(b*196+pos), o] = sum_c fmap[b,c,pos] * Wc[o,c]
//   M=25088 rows (b,pos), N=256 (full, so fmap is read exactly once),
//   K=1024, BK=64. Block 256 = 4 waves, wave w owns N-cols [w*64, w*64+64).
//   A-operand: fp32 fmap staged TRANSPOSED + converted to bf16 in LDS
//   (rows are pos-major in memory; lane = M-row so global loads coalesce
//   along pos). B-operand: Wc bf16 K-contiguous via gld16 (XOR-swizzled
//   source chunks, tight LDS as gld16 requires).
// ---------------------------------------------------------------------------
__global__ __launch_bounds__(256, 3) void posgemm_kernel(
    const float* __restrict__ fmap,         // (128,1024,196)
    const __hip_bfloat16* __restrict__ Wc,  // (256,1024)
    __hip_bfloat16* __restrict__ G)         // (25088,256)
{
    const int tid = threadIdx.x;
    const int wave = tid >> 6, lane = tid & 63;
    const int m16 = lane & 15, quad = lane >> 4;
    const int r0 = blockIdx.x * 64;

    // per-lane M-row decode (row = b*196 + pos); constant-div by 196
    const int r = r0 + lane;
    const int b_l = r / 196;
    const int pos_l = r - b_l * 196;
    const size_t abase = (size_t)b_l * (C_ * POS_) + pos_l;

    __shared__ __align__(16) __hip_bfloat16 As[64 * 66];   // [m][k] padded
    __shared__ __align__(16) __hip_bfloat16 Bs[256 * 64];  // tight (gld16)

    f32x4 acc[4][4];
    #pragma unroll
    for (int i = 0; i < 4; ++i)
        #pragma unroll
        for (int j = 0; j < 4; ++j)
            acc[i][j] = (f32x4){0.f, 0.f, 0.f, 0.f};

    for (int k0 = 0; k0 < 1024; k0 += 64) {
        // B: 2048 16B-chunks, 8 gld16 per lane. LDS chunk (mq,cq) holds
        // source chunk cq^(mq&7) of Wc row mq.
        #pragma unroll
        for (int jj = 0; jj < 8; ++jj) {
            int q = (wave * 8 + jj) * 64 + lane;
            int mq = q >> 3, cq = q & 7;
            int csq = cq ^ (mq & 7);
            gld16(Wc + (size_t)mq * 1024 + k0 + csq * 8,
                  (char*)Bs + (size_t)(wave * 8 + jj) * 1024);
        }
        // A: transpose+convert. Wave w covers c-offsets p*16+w*4 .. +3.
        #pragma unroll
        for (int p = 0; p < 4; ++p) {
            int cc = p * 16 + wave * 4;
            const float* fp = fmap + abase + (size_t)(k0 + cc) * POS_;
            float f0 = fp[0];
            float f1 = fp[POS_];
            float f2 = fp[2 * POS_];
            float f3 = fp[3 * POS_];
            __hip_bfloat162 q0, q1;
            q0.x = __float2bfloat16(f0); q0.y = __float2bfloat16(f1);
            q1.x = __float2bfloat16(f2); q1.y = __float2bfloat16(f3);
            *(__hip_bfloat162*)&As[lane * 66 + cc]     = q0;
            *(__hip_bfloat162*)&As[lane * 66 + cc + 2] = q1;
        }
        __syncthreads();
        #pragma unroll
        for (int ks = 0; ks < 2; ++ks) {
            bf16x8 af[4], bfv[4];
            #pragma unroll
            for (int i = 0; i < 4; ++i) {
                int m = i * 16 + m16;
                af[i] = *(const bf16x8*)&As[m * 66 + (ks * 4 + quad) * 8];
                int n = wave * 64 + i * 16 + m16;
                int cq2 = (ks * 4 + quad) ^ (n & 7);
                bfv[i] = *(const bf16x8*)&Bs[(n * 8 + cq2) * 8];
            }
            #pragma unroll
            for (int i = 0; i < 4; ++i)
                #pragma unroll
                for (int j = 0; j < 4; ++j)
                    acc[i][j] = __builtin_amdgcn_mfma_f32_16x16x32_bf16(
                        af[i], bfv[j], acc[i][j], 0, 0, 0);
        }
        __syncthreads();
    }

    // C/D layout: col = lane&15, row = quad*4 + reg
    #pragma unroll
    for (int i = 0; i < 4; ++i) {
        #pragma unroll
        for (int j = 0; j < 4; ++j) {
            int col = wave * 64 + j * 16 + m16;
            int rb = r0 + i * 16 + quad * 4;
            #pragma unroll
            for (int g = 0; g < 4; ++g)
                G[(size_t)(rb + g) * 256 + col] = __float2bfloat16(acc[i][j][g]);
        }
    }
}

// ---------------------------------------------------------------------------
// Kernel 3: roi2 — ROI-align on the 256 mixed channels of G -> feat fp32
//   grid (4 o-chunks, 128 batches), block 576 = 9 cells x 64 o-lanes.
//   Stage G[b, :, o0..o0+63] as LDS [pos][64 o] bf16 (tight: sampling reads
//   are same-pos across the wave -> 32 distinct dwords, conflict-free).
//   Tap math = r3/r6 recompute-in-VALU form (r4/r5: tables regress).
// ---------------------------------------------------------------------------
__global__ __launch_bounds__(576) void roi2_kernel(
    const __hip_bfloat16* __restrict__ G,   // (128*196, 256)
    const float* __restrict__ boxes,        // (128,8,4)
    float* __restrict__ feat)               // (1024, 2304) [bn][cell*256+o]
{
    const int b = blockIdx.y;
    const int o0 = blockIdx.x * 64;
    const int tid = threadIdx.x;
    const int l = tid & 63;
    const int cell = tid >> 6;          // 0..8
    const int ch = cell / 3, cw = cell % 3;
    __shared__ __align__(16) __hip_bfloat16 Ls[POS_ * 64];

    for (int idx = tid; idx < POS_ * 8; idx += 576) {
        int p = idx >> 3, chunk = idx & 7;
        const uint4* src = (const uint4*)(G +
            ((size_t)(b * POS_ + p) * 256 + o0 + chunk * 8));
        *(uint4*)&Ls[p * 64 + chunk * 8] = *src;
    }
    __syncthreads();

    for (int n = 0; n < N_; ++n) {
        const float* bx = boxes + (size_t)(b * N_ + n) * 4;
        float x1 = bx[0], y1 = bx[1], x2 = bx[2], y2 = bx[3];
        float bw = (x2 - x1) * (1.0f / 3.0f);
        float bh = (y2 - y1) * (1.0f / 3.0f);
        float acc = 0.0f;
        #pragma unroll
        for (int si = 0; si < 2; ++si) {
            float yy = y1 + ((float)(2 * ch + si) + 0.5f) * 0.5f * bh;
            #pragma unroll
            for (int sj = 0; sj < 2; ++sj) {
                float xx = x1 + ((float)(2 * cw + sj) + 0.5f) * 0.5f * bw;
                bool valid = (yy > -1.0f) && (yy < (float)FS_) &&
                             (xx > -1.0f) && (xx < (float)FS_);
                float y = fminf(fmaxf(yy, 0.0f), (float)(FS_ - 1));
                float x = fminf(fmaxf(xx, 0.0f), (float)(FS_ - 1));
                int y0 = (int)floorf(y);
                int x0 = (int)floorf(x);
                int y1i = min(y0 + 1, FS_ - 1);
                int x1i = min(x0 + 1, FS_ - 1);
                float ly = y - (float)y0, lx = x - (float)x0;
                float hy = 1.0f - ly,     hx = 1.0f - lx;
                float v00 = __bfloat162float(Ls[(y0  * FS_ + x0 ) * 64 + l]);
                float v01 = __bfloat162float(Ls[(y0  * FS_ + x1i) * 64 + l]);
                float v10 = __bfloat162float(Ls[(y1i * FS_ + x0 ) * 64 + l]);
                float v11 = __bfloat162float(Ls[(y1i * FS_ + x1i) * 64 + l]);
                float val = hy * hx * v00 + hy * lx * v01 +
                            ly * hx * v10 + ly * lx * v11;
                acc += valid ? val : 0.0f;
            }
        }
        feat[(size_t)(b * N_ + n) * FEATD_ + cell * 256 + o0 + l] = acc * 0.25f;
    }
}

// ---------------------------------------------------------------------------
// MFMA GEMM (fc1): h1 = relu(diff @ fc1_wp^T + b). 64x64 tile, BK=64.
// ---------------------------------------------------------------------------
__global__ __launch_bounds__(256) void fc1_gemm_kernel(
    const __hip_bfloat16* __restrict__ A,    // diff (1024 x 2304)
    const __hip_bfloat16* __restrict__ Bm,   // fc1_wp (1024 x 2304)
    const float* __restrict__ bias,
    float* __restrict__ C)                   // h1 (1024 x 1024)
{
    const int tid = threadIdx.x;
    const int wave = tid >> 6, lane = tid & 63;
    const int r0 = blockIdx.y * 64, n0 = blockIdx.x * 64;
    const int wm = (wave >> 1) * 32, wn = (wave & 1) * 32;
    const int m16 = lane & 15, quad = lane >> 4;
    const int K = FEATD_;
    __shared__ __align__(16) __hip_bfloat16 As[64 * 64];
    __shared__ __align__(16) __hip_bfloat16 Bs[64 * 64];

    f32x4 acc[2][2];
    #pragma unroll
    for (int i = 0; i < 2; ++i)
        #pragma unroll
        for (int j = 0; j < 2; ++j)
            acc[i][j] = (f32x4){0.f, 0.f, 0.f, 0.f};

    const int s0 = wave * 64 + lane;
    const int ms0 = s0 >> 3, cs0 = (s0 & 7) ^ (ms0 & 7);
    const int s1 = 256 + s0;
    const int ms1 = s1 >> 3, cs1 = (s1 & 7) ^ (ms1 & 7);
    const size_t rA0 = (size_t)(r0 + ms0) * K + cs0 * 8;
    const size_t rA1 = (size_t)(r0 + ms1) * K + cs1 * 8;
    const size_t rB0 = (size_t)(n0 + ms0) * K + cs0 * 8;
    const size_t rB1 = (size_t)(n0 + ms1) * K + cs1 * 8;

    for (int k0 = 0; k0 < K; k0 += 64) {
        gld16(A + rA0 + k0, &As[wave * 512]);
        gld16(Bm + rB0 + k0, &Bs[wave * 512]);
        gld16(A + rA1 + k0, &As[2048 + wave * 512]);
        gld16(Bm + rB1 + k0, &Bs[2048 + wave * 512]);
        __syncthreads();
        #pragma unroll
        for (int ks = 0; ks < 2; ++ks) {
            bf16x8 af[2], bfv[2];
            #pragma unroll
            for (int t = 0; t < 2; ++t) {
                int m = wm + t * 16 + m16;
                int cp = (ks * 4 + quad) ^ (m & 7);
                af[t] = *(const bf16x8*)&As[(m * 8 + cp) * 8];
                int n = wn + t * 16 + m16;
                int cq = (ks * 4 + quad) ^ (n & 7);
                bfv[t] = *(const bf16x8*)&Bs[(n * 8 + cq) * 8];
            }
            #pragma unroll
            for (int i = 0; i < 2; ++i)
                #pragma unroll
                for (int j = 0; j < 2; ++j)
                    acc[i][j] = __builtin_amdgcn_mfma_f32_16x16x32_bf16(
                        af[i], bfv[j], acc[i][j], 0, 0, 0);
        }
        __syncthreads();
    }

    #pragma unroll
    for (int i = 0; i < 2; ++i) {
        #pragma unroll
        for (int j = 0; j < 2; ++j) {
            int col = n0 + wn + j * 16 + m16;
            int rbase = r0 + wm + i * 16 + quad * 4;
            float bv = bias[col];
            #pragma unroll
            for (int g = 0; g < 4; ++g) {
                int r = rbase + g;
                float v = acc[i][j][g] + bv;
                C[(size_t)r * H1_ + col] = v > 0.f ? v : 0.f;
            }
        }
    }
}

// ---------------------------------------------------------------------------
// fc1_w (1024 x 2304 fp32, k = o*9+hw) -> bf16 permuted (k' = hw*256+o)
// ---------------------------------------------------------------------------
__global__ __launch_bounds__(256) void fc1w_perm_kernel(
    const float* __restrict__ src, __hip_bfloat16* __restrict__ dst)
{
    int h = blockIdx.y;
    int d2 = blockIdx.x * 256 + threadIdx.x;   // hw*256+o
    int hw = d2 >> 8, o = d2 & 255;
    dst[(size_t)h * FEATD_ + d2] =
        __float2bfloat16(src[(size_t)h * FEATD_ + o * HWC_ + hw]);
}

// ---------------------------------------------------------------------------
// inv[b][p] = n with pids[b][n]==p else -1
// ---------------------------------------------------------------------------
__global__ __launch_bounds__(64) void invmap_kernel(
    const int* __restrict__ pids, int* __restrict__ inv)
{
    int b = blockIdx.x;
    int p = threadIdx.x;
    if (p < P_) {
        int v = -1;
        for (int n = 0; n < N_; ++n)
            if (pids[b * N_ + n] == p) v = n;
        inv[b * P_ + p] = v;
    }
}

// ---------------------------------------------------------------------------
// mean_b[p][d] = (1/128) sum_b feat[b, inv[b][p], d]
// ---------------------------------------------------------------------------
__global__ __launch_bounds__(256) void meanb_kernel(
    const float* __restrict__ feat, const int* __restrict__ inv,
    float* __restrict__ mean_b)
{
    int p = blockIdx.x;
    int d = blockIdx.y * 256 + threadIdx.x;
    float acc = 0.0f;
    for (int b = 0; b < B_; ++b) {
        int n = inv[b * P_ + p];
        if (n >= 0) acc += feat[(size_t)(b * N_ + n) * FEATD_ + d];
    }
    mean_b[(size_t)p * FEATD_ + d] = acc * (1.0f / (float)B_);
}

// ---------------------------------------------------------------------------
// diff_bf16[r][d] = bf16(mean_b[pids[r]][d] - feat[r][d])
// ---------------------------------------------------------------------------
__global__ __launch_bounds__(256) void diff_kernel(
    const float* __restrict__ feat, const float* __restrict__ mean_b,
    const int* __restrict__ pids, __hip_bfloat16* __restrict__ diff)
{
    int r = blockIdx.x;
    int pid = pids[r];
    const float* fr = feat + (size_t)r * FEATD_;
    const float* mr = mean_b + (size_t)pid * FEATD_;
    __hip_bfloat16* dr = diff + (size_t)r * FEATD_;
    for (int d = threadIdx.x; d < FEATD_; d += 256)
        dr[d] = __float2bfloat16(mr[d] - fr[d]);
}

// ---------------------------------------------------------------------------
// fc2: out[bn][o] = h1[bn] . fc2_w[o] + fc2_b[o]
// ---------------------------------------------------------------------------
__global__ __launch_bounds__(256) void fc2_kernel(
    const float* __restrict__ h1, const float* __restrict__ fc2_w,
    const float* __restrict__ fc2_b, float* __restrict__ out)
{
    int bn = blockIdx.x;
    int tid = threadIdx.x;
    __shared__ __align__(16) float row[H1_];
    __shared__ float partial[32][8];
    ((float4*)row)[tid] = ((const float4*)(h1 + (size_t)bn * H1_))[tid];
    __syncthreads();
    int o = tid >> 3, part = tid & 7;
    float acc = 0.0f;
    if (o < O_) {
        const float* wrow = fc2_w + (size_t)o * H1_ + part * 128;
        const float* hrow = row + part * 128;
        #pragma unroll 4
        for (int j = 0; j < 128; ++j) acc += hrow[j] * wrow[j];
    }
    partial[o][part] = acc;
    __syncthreads();
    if (part == 0 && o < O_) {
        float s = fc2_b[o];
        #pragma unroll
        for (int p = 0; p < 8; ++p) s += partial[o][p];
        out[(size_t)bn * O_ + o] = s;
    }
}

// ---------------------------------------------------------------------------
// Launch
// ---------------------------------------------------------------------------
extern "C" void kernel_launch(void* const* d_in, const int* in_sizes, int n_in,
                              void* d_out, int out_size, void* d_ws, size_t ws_size,
                              hipStream_t stream) {
    const float* fmap  = (const float*)d_in[0];
    const float* boxes = (const float*)d_in[1];
    const int*   pids  = (const int*)  d_in[2];
    const float* w1    = (const float*)d_in[3];
    const float* w2    = (const float*)d_in[4];
    const float* fc1_w = (const float*)d_in[5];
    const float* fc1_b = (const float*)d_in[6];
    const float* fc2_w = (const float*)d_in[7];
    const float* fc2_b = (const float*)d_in[8];
    float* out = (float*)d_out;

    // workspace layout (all 16B aligned)
    char* wsb = (char*)d_ws;
    __hip_bfloat16* Wc    = (__hip_bfloat16*)wsb;                       // 256*1024
    __hip_bfloat16* G     = Wc + 256 * 1024;                            // 25088*256
    __hip_bfloat16* fc1wp = G + (size_t)GROWS_ * 256;                   // 1024*2304
    __hip_bfloat16* diffp = fc1wp + (size_t)H1_ * FEATD_;               // 1024*2304
    float* feat   = (float*)(diffp + (size_t)H1_ * FEATD_);             // 1024*2304
    float* mean_b = feat + (size_t)(B_ * N_) * FEATD_;                  // 20*2304
    float* h1     = mean_b + (size_t)P_ * FEATD_;                       // 1024*1024
    int*   inv    = (int*)(h1 + (size_t)(B_ * N_) * H1_);               // 128*20
    float* wpart  = (float*)(inv + 128 * P_ + 64);                      // 8*256*1024

    hipLaunchKernelGGL(wcombine_split_kernel, dim3(16, 4, 8), dim3(256), 0, stream,
                       w1, w2, wpart);
    hipLaunchKernelGGL(wc_reduce_kernel, dim3(1024), dim3(256), 0, stream,
                       wpart, Wc);
    hipLaunchKernelGGL(posgemm_kernel, dim3(GROWS_ / 64), dim3(256), 0, stream,
                       fmap, Wc, G);
    hipLaunchKernelGGL(roi2_kernel, dim3(4, 128), dim3(576), 0, stream,
                       G, boxes, feat);
    hipLaunchKernelGGL(fc1w_perm_kernel, dim3(9, 1024), dim3(256), 0, stream,
                       fc1_w, fc1wp);
    hipLaunchKernelGGL(invmap_kernel, dim3(128), dim3(64), 0, stream,
                       pids, inv);
    hipLaunchKernelGGL(meanb_kernel, dim3(20, 9), dim3(256), 0, stream,
                       feat, inv, mean_b);
    hipLaunchKernelGGL(diff_kernel, dim3(1024), dim3(256), 0, stream,
                       feat, mean_b, pids, diffp);
    hipLaunchKernelGGL(fc1_gemm_kernel, dim3(16, 16), dim3(256), 0, stream,
                       diffp, fc1wp, fc1_b, h1);
    hipLaunchKernelGGL(fc2_kernel, dim3(1024), dim3(256), 0, stream,
                       h1, fc2_w, fc2_b, out);
}